// Round 15
// baseline (259.429 us; speedup 1.0000x reference)
//
#include <hip/hip_runtime.h>
#include <cstdint>
#include <cstddef>

#define N_  32
#define C_  64
#define T_  256
#define V_  25
#define R_  8
#define O_  64
#define K_  5
#define NU_ 17
#define U_  25
#define CV  (C_ * V_)        // 1600
#define OG  2                // o's per k_main block
#define TBLK 64              // t's per k_main block

#define OUT_ELEMS ((size_t)N_ * O_ * T_ * V_)   // 13,107,200

typedef __attribute__((ext_vector_type(8))) short bf16x8;
typedef __attribute__((ext_vector_type(4))) float f32x4;

static __device__ __forceinline__ unsigned short f2bf(float f) {
    union { float f; unsigned u; } c; c.f = f;
    return (unsigned short)((c.u + 0x8000u) >> 16);
}
static __device__ __forceinline__ float bf2f(unsigned short h) {
    union { unsigned u; float f; } c; c.u = ((unsigned)h) << 16; return c.f;
}
static __device__ __forceinline__ unsigned pk2(float a, float b) {
    union { float f; unsigned u; } ca, cb; ca.f = a; cb.f = b;
    return ((ca.u + 0x8000u) >> 16) | ((cb.u + 0x8000u) & 0xFFFF0000u);
}
static __device__ __forceinline__ bf16x8 asbf(uint4 u) {
    union { uint4 u; bf16x8 h; } c; c.u = u; return c.h;
}

// ---------------------------------------------------------------------------
// k_xcast: fragment-native xT3 with cv' = v*64+c ordering:
//   xT3[n][tt(16)][s'(200)][tl(16)][ke(8)],  s' = v*8 + c/8, ke = c&7.
// ---------------------------------------------------------------------------
__global__ void k_xcast(const float* __restrict__ x, unsigned short* __restrict__ xT3,
                        float* __restrict__ pp) {
    __shared__ unsigned short tile[C_][408];   // [c][t*25+v], row 816 B
    int bid = blockIdx.x;
    int n = bid >> 4, tb = bid & 15;
    int tid = threadIdx.x;
    const float* xb = x + (size_t)n * C_ * T_ * V_ + tb * 400;
#pragma unroll
    for (int it = 0; it < 25; ++it) {
        int i = it * 256 + tid;          // < 6400
        int c = i / 100, q = i - c * 100;
        float4 v4 = *(const float4*)(xb + (size_t)c * (T_ * V_) + q * 4);
        uint2 w;
        w.x = pk2(v4.x, v4.y);
        w.y = pk2(v4.z, v4.w);
        *(uint2*)&tile[c][q * 4] = w;
    }
    __syncthreads();
    unsigned short* dstb = xT3 + ((size_t)(n * 16 + tb) * 200) * 128;
    for (int i = tid; i < 200 * 16; i += 256) {
        int sp = i >> 4, tl = i & 15;
        int v = sp >> 3, c0 = (sp & 7) * 8;
        unsigned short h[8];
#pragma unroll
        for (int j = 0; j < 8; ++j) h[j] = tile[c0 + j][tl * 25 + v];
        uint4 pk;
        pk.x = (unsigned)h[0] | ((unsigned)h[1] << 16);
        pk.y = (unsigned)h[2] | ((unsigned)h[3] << 16);
        pk.z = (unsigned)h[4] | ((unsigned)h[5] << 16);
        pk.w = (unsigned)h[6] | ((unsigned)h[7] << 16);
        *(uint4*)(dstb + (size_t)sp * 128 + tl * 8) = pk;
    }
    float* ppd = pp + ((size_t)n * 16 + tb) * CV;
    for (int e = tid; e < CV; e += 256) {
        int c = e / 25, v = e - c * 25;
        float s = 0.f;
#pragma unroll
        for (int t = 0; t < 16; ++t) s += bf2f(tile[c][t * 25 + v]);
        ppd[e] = s;
    }
}

// classic pool (slow tier)
__global__ void k_pool(const float* __restrict__ x, float* __restrict__ pool) {
    int nc = blockIdx.x;
    int t  = threadIdx.x;
    const float* px = x + ((size_t)nc * T_ + t) * V_;
    float acc[V_];
#pragma unroll
    for (int v = 0; v < V_; ++v) acc[v] = px[v];
#pragma unroll
    for (int off = 32; off > 0; off >>= 1) {
#pragma unroll
        for (int v = 0; v < V_; ++v) acc[v] += __shfl_down(acc[v], off, 64);
    }
    __shared__ float sm[4][V_];
    int wave = t >> 6, lane = t & 63;
    if (lane == 0) {
#pragma unroll
        for (int v = 0; v < V_; ++v) sm[wave][v] = acc[v];
    }
    __syncthreads();
    if (t < V_) {
        float s = sm[0][t] + sm[1][t] + sm[2][t] + sm[3][t];
        pool[(size_t)nc * V_ + t] = s * (1.0f / T_);
    }
}

// ---------------------------------------------------------------------------
// k_tvals (slow tier only)
// ---------------------------------------------------------------------------
__global__ void k_tvals(const float* __restrict__ pool,
                        const float* __restrict__ W11, const float* __restrict__ b11,
                        const float* __restrict__ W12, const float* __restrict__ b12,
                        const float* __restrict__ W2,  const float* __restrict__ b2,
                        float* __restrict__ t2o, float* __restrict__ tSo) {
    int kn = blockIdx.x;
    int k = kn / N_, n = kn % N_;
    int tid = threadIdx.x;
    int r = tid >> 5, v = tid & 31;
    if (v >= V_) return;
    const float* pp = pool + (size_t)n * C_ * V_ + v;
    const float* w2 = W2 + ((size_t)k * R_ + r) * C_;
    const float* w1 = ((v < NU_) ? W11 : W12) + ((size_t)k * R_ + r) * C_;
    float a2 = b2[k * R_ + r];
    float a1 = (v < NU_) ? b11[k * R_ + r] : b12[k * R_ + r];
    for (int c = 0; c < C_; ++c) {
        float p = pp[(size_t)c * V_];
        a2 += w2[c] * p;
        a1 += w1[c] * p;
    }
    size_t idx = (((size_t)k * N_ + n) * R_ + r) * V_ + v;
    t2o[idx] = a2;
    tSo[idx] = a1;
}

// ---------------------------------------------------------------------------
// k_graphs (slow tier)
// ---------------------------------------------------------------------------
__global__ void k_graphs(const float* __restrict__ t2v, const float* __restrict__ tSv,
                         const float* __restrict__ W4, const float* __restrict__ b4,
                         float* __restrict__ graphs) {
    int kn = blockIdx.x;
    int k = kn / N_, n = kn % N_;
    int kup = (k + 1) % K_;
    __shared__ float F[R_][V_ * V_];
    __shared__ float w4s[O_][R_];
    __shared__ float b4s[O_];
    int tid = threadIdx.x;
    for (int i = tid; i < O_ * R_; i += 256) w4s[i / R_][i % R_] = W4[(size_t)k * O_ * R_ + i];
    if (tid < O_) b4s[tid] = b4[k * O_ + tid];
    for (int idx = tid; idx < R_ * V_ * V_; idx += 256) {
        int r = idx / (V_ * V_), uv = idx % (V_ * V_);
        int u = uv / V_, v = uv % V_;
        int ks = (u < NU_) ? kup : k;
        size_t base = (((size_t)ks * N_ + n) * R_ + r) * V_;
        F[r][uv] = tanhf(tSv[base + u] - t2v[base + v]);
    }
    __syncthreads();
    float* gout = graphs + ((size_t)k * N_ + n) * O_ * (V_ * V_);
    for (int idx = tid; idx < O_ * V_ * V_; idx += 256) {
        int o = idx / (V_ * V_), uv = idx % (V_ * V_);
        float a = b4s[o];
#pragma unroll
        for (int r = 0; r < R_; ++r) a += w4s[o][r] * F[r][uv];
        gout[idx] = a;
    }
}

// ---------------------------------------------------------------------------
// k_graphs2c (fast tier): pool-from-pp + tvals + F + graphs, fused; split
// over 2 o-halves for occupancy.
// ---------------------------------------------------------------------------
__global__ void k_graphs2c(const float* __restrict__ pp,
                           const float* __restrict__ W11, const float* __restrict__ b11,
                           const float* __restrict__ W12, const float* __restrict__ b12,
                           const float* __restrict__ W2,  const float* __restrict__ b2,
                           const float* __restrict__ W4,  const float* __restrict__ b4,
                           float* __restrict__ graphs) {
    int bid = blockIdx.x;
    int og = bid & 1;
    int kn = bid >> 1;
    int k = kn / N_, n = kn % N_;
    int kup = (k + 1) % K_;
    __shared__ float poolL[CV];
    __shared__ float t2s[2][R_][V_];
    __shared__ float tSs[2][R_][V_];
    __shared__ float F[R_][V_ * V_];
    __shared__ float w4s[O_][R_];
    __shared__ float b4s[O_];
    int tid = threadIdx.x;
    for (int i = tid; i < O_ * R_; i += 512) w4s[i / R_][i % R_] = W4[(size_t)k * O_ * R_ + i];
    if (tid < O_) b4s[tid] = b4[k * O_ + tid];
    const float* ppn = pp + (size_t)n * 16 * CV;
    for (int i = tid; i < CV; i += 512) {
        float s = 0.f;
#pragma unroll
        for (int tb = 0; tb < 16; ++tb) s += ppn[(size_t)tb * CV + i];
        poolL[i] = s * (1.0f / T_);
    }
    __syncthreads();
    for (int i = tid; i < 2 * R_ * V_; i += 512) {
        int ks = i / (R_ * V_);
        int rem = i - ks * (R_ * V_);
        int r = rem / V_, v = rem - r * V_;
        int kk = ks ? kup : k;
        const float* w2 = W2 + ((size_t)kk * R_ + r) * C_;
        const float* w1 = ((v < NU_) ? W11 : W12) + ((size_t)kk * R_ + r) * C_;
        float a2 = b2[kk * R_ + r];
        float a1 = (v < NU_) ? b11[kk * R_ + r] : b12[kk * R_ + r];
        for (int c = 0; c < C_; ++c) {
            float p = poolL[c * 25 + v];
            a2 += w2[c] * p;
            a1 += w1[c] * p;
        }
        t2s[ks][r][v] = a2;
        tSs[ks][r][v] = a1;
    }
    __syncthreads();
    for (int idx = tid; idx < R_ * V_ * V_; idx += 512) {
        int r = idx / (V_ * V_), uv = idx % (V_ * V_);
        int u = uv / V_, v = uv % V_;
        int ks = (u < NU_) ? 1 : 0;
        F[r][uv] = tanhf(tSs[ks][r][u] - t2s[ks][r][v]);
    }
    __syncthreads();
    float* gout = graphs + ((size_t)k * N_ + n) * O_ * (V_ * V_);
    const int half = O_ * V_ * V_ / 2;
    for (int idx = og * half + tid; idx < (og + 1) * half; idx += 512) {
        int o = idx / (V_ * V_), uv = idx % (V_ * V_);
        float a = b4s[o];
#pragma unroll
        for (int r = 0; r < R_; ++r) a += w4s[o][r] * F[r][uv];
        gout[idx] = a;
    }
}

// ---------------------------------------------------------------------------
// k_main_fast (FACTORED two-GEMM formulation, 11.7 GFLOP vs 53.7):
//   stage A: x2[k,o,t,v] = sum_c W3[k,o,c] * x[c,t,v]
//     GEMM M=1600 ((t,v) packed), N=10 (k*2+o, pad 16), K=64 (c).
//     A-frags per-lane from global xT3; W3 B-frags hoisted to 2 regs.
//     C/D -> bf16 -> x2s LDS [o][t][kv=k*25+v], XOR-swizzled rows.
//   stage B: out[o,t,u] = bias + sum_kv x2[o][t][kv] * G[k,o,u,v]
//     per o: GEMM M=64(t), N=25(u pad 32), K=125(kv pad 128).
//     B = GtL[o][u][kv] bf16, XOR-swizzled; A = x2s.
// Block = (n, tb of 64 t, og of 2 o), 256 thr (4 waves), 3 barriers total.
// Grid 4096, XCD-swizzled so each XCD's blocks share 16 (n,tb) x-panels.
// LDS ~51.5 KB -> 3 blocks/CU. WRITE_SIZE is the spill watchdog.
// ---------------------------------------------------------------------------
__global__ __launch_bounds__(256, 3) void k_main_fast(
    const unsigned short* __restrict__ xT3,  // [N][16][200][16][8] bf16 bits
    const float* __restrict__ graphs,        // [K][N][O][625]
    const float* __restrict__ Adj,           // [K][625]
    const float* __restrict__ W3,            // [K][O][C]
    const float* __restrict__ b3,            // [K][O]
    float* __restrict__ out) {

    __shared__ unsigned short x2s[OG][TBLK][128];  // 32 KB, row swz ^((t&7)<<4)
    __shared__ unsigned short GtL[OG][32][128];    // 16 KB, row swz ^((u&7)<<4)
    __shared__ unsigned short W3L[16][64];         //  2 KB: [ncol=k*2+o][c]
    __shared__ float biasS[OG][32];                // 256 B

    const int tid = threadIdx.x;
    int raw = blockIdx.x;
    int bidn = (raw & 7) * 512 + (raw >> 3);   // XCD swizzle (4096 % 8 == 0)
    const int og = bidn & 31;
    const int tb = (bidn >> 5) & 3;
    const int n  = bidn >> 7;
    const int obase = og * OG;
    const int tgb = tb * TBLK;
    const int lane = tid & 63;
    const int wv_ = tid >> 6;       // 0..3
    const int lr = lane & 15;
    const int eg = lane >> 4;

    // ---- phase 0: zero pads (whole buffers), fill W3L rows 0..9 ----
    {
        uint4 z; z.x = z.y = z.z = z.w = 0u;
        for (int i = tid; i < (OG * TBLK * 128) / 8; i += 256) ((uint4*)x2s)[i] = z;      // 8 it
        for (int i = tid; i < (OG * 32 * 128) / 8; i += 256) ((uint4*)GtL)[i] = z;        // 4 it
        if (tid < 48) ((uint4*)&W3L[10][0])[tid] = z;       // rows 10..15
        for (int i = tid; i < 10 * C_; i += 256) {          // rows 0..9: ncol=k*2+o
            int ncol = i >> 6, c = i & 63;
            int k = ncol >> 1, o = ncol & 1;
            W3L[ncol][c] = f2bf(W3[((size_t)k * O_ + obase + o) * C_ + c]);
        }
    }
    __syncthreads();

    // ---- phase 1a: stage GtL (bf16 G, swizzled) ----
    const size_t kstride = (size_t)N_ * O_ * 625;
    if (tid < OG * K_ * 25) {       // 250: (o, k, u)
        int o = tid / 125;
        int rem = tid - o * 125;
        int k = rem / 25, u = rem - k * 25;
        const float* gp = graphs + (size_t)k * kstride + ((size_t)n * O_ + obase + o) * 625 + u * 25;
        const float* ap = Adj + k * 625 + u * 25;
        char* rowb = (char*)GtL + (o * 32 + u) * 256;
        const int swz = (u & 7) << 4;
#pragma unroll
        for (int v = 0; v < V_; ++v) {
            float g = gp[v] + ap[v];
            *(unsigned short*)(rowb + (((k * 25 + v) * 2) ^ swz)) = f2bf(g);
        }
    }

    // ---- phase 1b: stage A (MFMA) -> x2s ----
    {
        bf16x8 wb0 = *(const bf16x8*)&W3L[lr][eg * 8];        // ks0: c = eg*8+e
        bf16x8 wb1 = *(const bf16x8*)&W3L[lr][32 + eg * 8];   // ks1
        const unsigned short* Axb = xT3 + (size_t)n * (T_ * CV);
        const int kA = (lr < 10) ? (lr >> 1) : 0;
        const int oA = lr & 1;
        for (int i = 0; i < 25; ++i) {
            int mt = wv_ * 25 + i;
            int row = mt * 16 + lr;
            int t = (row * 5243) >> 17;          // /25
            int v = row - t * 25;
            int tg = tgb + t;
            const unsigned short* pA = Axb + ((size_t)((tg >> 4) * 200 + v * 8 + eg)) * 128 + (tg & 15) * 8;
            uint4 a0 = *(const uint4*)pA;               // c-group eg
            uint4 a1 = *(const uint4*)(pA + 4 * 128);   // c-group 4+eg
            f32x4 acc = {0.f, 0.f, 0.f, 0.f};
            acc = __builtin_amdgcn_mfma_f32_16x16x32_bf16(asbf(a0), wb0, acc, 0, 0, 0);
            acc = __builtin_amdgcn_mfma_f32_16x16x32_bf16(asbf(a1), wb1, acc, 0, 0, 0);
            if (lr < 10) {
#pragma unroll
                for (int r2 = 0; r2 < 4; ++r2) {
                    int rw = mt * 16 + eg * 4 + r2;
                    int tw = (rw * 5243) >> 17;
                    int vw = rw - tw * 25;
                    int byte = (oA * TBLK + tw) * 256 + ((((kA * 25 + vw) * 2)) ^ ((tw & 7) << 4));
                    *(unsigned short*)((char*)x2s + byte) = f2bf(acc[r2]);
                }
            }
        }
    }
    __syncthreads();

    // ---- phase 2: bias[o][u] = sum_k b3[k,o] * sum_v G ----
    if (tid < OG * 25) {
        int o = tid / 25, u = tid - o * 25;
        const char* rowb = (const char*)GtL + (o * 32 + u) * 256;
        const int swz = (u & 7) << 4;
        float bv = 0.f;
#pragma unroll
        for (int k = 0; k < K_; ++k) {
            float sk = 0.f;
            for (int v = 0; v < V_; ++v)
                sk += bf2f(*(const unsigned short*)(rowb + (((k * 25 + v) * 2) ^ swz)));
            bv += sk * b3[k * O_ + obase + o];
        }
        biasS[o][u] = bv;
    }
    __syncthreads();

    // ---- phase 3: stage B + epilogue (2 units/wave: unit = o*4 + mt) ----
#pragma unroll
    for (int uu = 0; uu < 2; ++uu) {
        int unit = wv_ * 2 + uu;
        int o = unit >> 2, mt = unit & 3;
        int t = mt * 16 + lr;
        f32x4 acc0 = {0.f, 0.f, 0.f, 0.f};
        f32x4 acc1 = {0.f, 0.f, 0.f, 0.f};
        const int aswz = (t & 7) << 4;
        const int bswz = (lr & 7) << 4;      // u&7 == lr&7 for both nt
#pragma unroll
        for (int ks = 0; ks < 4; ++ks) {
            int col = ks * 64 + eg * 16;
            bf16x8 a  = *(const bf16x8*)((const char*)x2s + (o * TBLK + t) * 256 + (col ^ aswz));
            bf16x8 b0 = *(const bf16x8*)((const char*)GtL + (o * 32 + lr) * 256 + (col ^ bswz));
            bf16x8 b1 = *(const bf16x8*)((const char*)GtL + (o * 32 + 16 + lr) * 256 + (col ^ bswz));
            acc0 = __builtin_amdgcn_mfma_f32_16x16x32_bf16(a, b0, acc0, 0, 0, 0);
            acc1 = __builtin_amdgcn_mfma_f32_16x16x32_bf16(a, b1, acc1, 0, 0, 0);
        }
        float* ob = out + ((size_t)n * O_ + obase + o) * T_ * V_;
#pragma unroll
        for (int nt = 0; nt < 2; ++nt) {
            f32x4 ac = nt ? acc1 : acc0;
            int u = nt * 16 + lr;
            if (u < U_) {
                float bv = biasS[o][u];
#pragma unroll
                for (int r2 = 0; r2 < 4; ++r2) {
                    int tl2 = mt * 16 + eg * 4 + r2;
                    ob[(size_t)(tgb + tl2) * V_ + u] = ac[r2] + bv;
                }
            }
        }
    }
}

// ---------------------------------------------------------------------------
// k_main_slow (fallback, proven R2 path)
// ---------------------------------------------------------------------------
#define OB 4
#define TB 64
__global__ __launch_bounds__(256, 1) void k_main_slow(
    const float* __restrict__ x, const float* __restrict__ graphs,
    const float* __restrict__ A, const float* __restrict__ W3,
    const float* __restrict__ b3, float* __restrict__ out) {
    int bid = blockIdx.x;
    int tb = bid & 3;
    int ob = (bid >> 2) & 15;
    int n  = bid >> 6;
    int tid = threadIdx.x;
    int ol = tid >> 6;
    int tl = tid & 63;
    int t = tb * TB + tl;
    int o = ob * OB + ol;

    __shared__ float Gs[K_][OB][V_][28];
    __shared__ float W3s[K_][OB][C_];
    __shared__ float b3s[K_][OB];

    for (int i = tid; i < K_ * OB * V_ * V_; i += 256) {
        int k   = i / (OB * V_ * V_);
        int rem = i % (OB * V_ * V_);
        int oo  = rem / (V_ * V_);
        int uv  = rem % (V_ * V_);
        Gs[k][oo][uv / V_][uv % V_] =
            graphs[(((size_t)k * N_ + n) * O_ + ob * OB + oo) * (V_ * V_) + uv]
            + A[k * V_ * V_ + uv];
    }
    for (int i = tid; i < K_ * OB * C_; i += 256) {
        int k   = i / (OB * C_);
        int rem = i % (OB * C_);
        int oo  = rem / C_, c = rem % C_;
        W3s[k][oo][c] = W3[((size_t)k * O_ + ob * OB + oo) * C_ + c];
    }
    if (tid < K_ * OB) b3s[tid / OB][tid % OB] = b3[(tid / OB) * O_ + ob * OB + tid % OB];
    __syncthreads();

    float x2[K_][V_];
#pragma unroll
    for (int k = 0; k < K_; ++k)
#pragma unroll
        for (int v = 0; v < V_; ++v) x2[k][v] = b3s[k][ol];

    const float* xb = x + ((size_t)n * C_ * T_ + t) * V_;
    for (int c = 0; c < C_; ++c) {
        const float* p = xb + (size_t)c * T_ * V_;
        float xv[V_];
#pragma unroll
        for (int v = 0; v < V_; ++v) xv[v] = p[v];
#pragma unroll
        for (int k = 0; k < K_; ++k) {
            float w = W3s[k][ol][c];
#pragma unroll
            for (int v = 0; v < V_; ++v) x2[k][v] += w * xv[v];
        }
    }

    float acc[V_];
#pragma unroll
    for (int u = 0; u < V_; ++u) acc[u] = 0.0f;
#pragma unroll
    for (int k = 0; k < K_; ++k) {
#pragma unroll
        for (int u = 0; u < V_; ++u) {
            const float* gr = &Gs[k][ol][u][0];
            float s = 0.0f;
#pragma unroll
            for (int v = 0; v < V_; ++v) s += gr[v] * x2[k][v];
            acc[u] += s;
        }
    }
    float* po = out + (((size_t)n * O_ + o) * T_ + t) * V_;
#pragma unroll
    for (int u = 0; u < V_; ++u) po[u] = acc[u];
}

// ---------------------------------------------------------------------------
extern "C" void kernel_launch(void* const* d_in, const int* in_sizes, int n_in,
                              void* d_out, int out_size, void* d_ws, size_t ws_size,
                              hipStream_t stream) {
    const float* x   = (const float*)d_in[0];
    const float* A   = (const float*)d_in[1];
    const float* W11 = (const float*)d_in[2];
    const float* b11 = (const float*)d_in[3];
    const float* W12 = (const float*)d_in[4];
    const float* b12 = (const float*)d_in[5];
    const float* W2  = (const float*)d_in[6];
    const float* b2  = (const float*)d_in[7];
    const float* W3  = (const float*)d_in[8];
    const float* b3  = (const float*)d_in[9];
    const float* W4  = (const float*)d_in[10];
    const float* b4  = (const float*)d_in[11];

    float* out    = (float*)d_out;
    float* graphs = out + OUT_ELEMS;   // second tuple element

    const size_t xT_bytes = sizeof(unsigned short) * (size_t)N_ * T_ * CV;  // 26.2 MB
    const size_t pp_bytes = sizeof(float) * (size_t)N_ * 16 * CV;           //  3.3 MB
    const size_t hdr      = (size_t)(1 << 20);
    const bool fast = (ws_size >= hdr + xT_bytes + pp_bytes);

    const size_t poolElems = (size_t)N_ * C_ * V_;      // 51,200
    const size_t tElems    = (size_t)K_ * N_ * R_ * V_; // 32,000
    const size_t slowNeed  = (poolElems + 2 * tElems) * sizeof(float);

    float* scratch = (fast || ws_size >= slowNeed) ? (float*)d_ws : out;
    float* pool = scratch;
    float* t2v  = scratch + poolElems;
    float* tSv  = t2v + tElems;
    unsigned short* xT3 = (unsigned short*)((char*)d_ws + hdr);
    float* pp = (float*)((char*)d_ws + hdr + xT_bytes);

    if (fast) {
        k_xcast   <<<N_ * 16, 256, 0, stream>>>(x, xT3, pp);
        k_graphs2c<<<K_ * N_ * 2, 512, 0, stream>>>(pp, W11, b11, W12, b12, W2, b2, W4, b4, graphs);
        k_main_fast<<<N_ * 4 * (O_ / OG), 256, 0, stream>>>(xT3, graphs, A, W3, b3, out);
    } else {
        k_pool  <<<N_ * C_, 256, 0, stream>>>(x, pool);
        k_tvals <<<K_ * N_, 256, 0, stream>>>(pool, W11, b11, W12, b12, W2, b2, t2v, tSv);
        k_graphs<<<K_ * N_, 256, 0, stream>>>(t2v, tSv, W4, b4, graphs);
        k_main_slow<<<N_ * (O_ / OB) * 4, 256, 0, stream>>>(x, graphs, A, W3, b3, out);
    }
}

// Round 16
// 109.381 us; speedup vs baseline: 2.3718x; 2.3718x over previous
//
#include <hip/hip_runtime.h>
#include <cstdint>
#include <cstddef>

#define N_  32
#define C_  64
#define T_  256
#define V_  25
#define R_  8
#define O_  64
#define K_  5
#define NU_ 17
#define U_  25
#define CV  (C_ * V_)        // 1600
#define OG  2                // o's per block in k_main
#define NB  (OG * 32)        // 64 ncols

#define OUT_ELEMS ((size_t)N_ * O_ * T_ * V_)   // 13,107,200

typedef __attribute__((ext_vector_type(8))) short bf16x8;
typedef __attribute__((ext_vector_type(4))) float f32x4;

// round-to-nearest-away, 2 ops
static __device__ __forceinline__ unsigned short f2bf(float f) {
    union { float f; unsigned u; } c; c.f = f;
    return (unsigned short)((c.u + 0x8000u) >> 16);
}
static __device__ __forceinline__ float bf2f(unsigned short h) {
    union { unsigned u; float f; } c; c.u = ((unsigned)h) << 16; return c.f;
}
static __device__ __forceinline__ float bf_lo(unsigned d) {
    union { unsigned u; float f; } c; c.u = d << 16; return c.f;
}
static __device__ __forceinline__ float bf_hi(unsigned d) {
    union { unsigned u; float f; } c; c.u = d & 0xFFFF0000u; return c.f;
}
static __device__ __forceinline__ unsigned pk2(float a, float b) {
    union { float f; unsigned u; } ca, cb; ca.f = a; cb.f = b;
    return ((ca.u + 0x8000u) >> 16) | ((cb.u + 0x8000u) & 0xFFFF0000u);
}
// single-instruction packed f32->bf16 (RNE)
static __device__ __forceinline__ unsigned cvtpk(float a, float b) {
    unsigned r;
    asm("v_cvt_pk_bf16_f32 %0, %1, %2" : "=v"(r) : "v"(a), "v"(b));
    return r;
}

// ---------------------------------------------------------------------------
// k_xcast: fragment-native xT3 with cv' = v*64+c ordering:
//   xT3[n][tt(16)][s'(200)][tl(16)][ke(8)],  s' = v*8 + c/8, ke = c&7.
// ---------------------------------------------------------------------------
__global__ void k_xcast(const float* __restrict__ x, unsigned short* __restrict__ xT3,
                        float* __restrict__ pp) {
    __shared__ unsigned short tile[C_][408];   // [c][t*25+v], row 816 B
    int bid = blockIdx.x;
    int n = bid >> 4, tb = bid & 15;
    int tid = threadIdx.x;
    const float* xb = x + (size_t)n * C_ * T_ * V_ + tb * 400;
#pragma unroll
    for (int it = 0; it < 25; ++it) {
        int i = it * 256 + tid;          // < 6400
        int c = i / 100, q = i - c * 100;
        float4 v4 = *(const float4*)(xb + (size_t)c * (T_ * V_) + q * 4);
        uint2 w;
        w.x = pk2(v4.x, v4.y);
        w.y = pk2(v4.z, v4.w);
        *(uint2*)&tile[c][q * 4] = w;
    }
    __syncthreads();
    unsigned short* dstb = xT3 + ((size_t)(n * 16 + tb) * 200) * 128;
    for (int i = tid; i < 200 * 16; i += 256) {
        int sp = i >> 4, tl = i & 15;
        int v = sp >> 3, c0 = (sp & 7) * 8;
        unsigned short h[8];
#pragma unroll
        for (int j = 0; j < 8; ++j) h[j] = tile[c0 + j][tl * 25 + v];
        uint4 pk;
        pk.x = (unsigned)h[0] | ((unsigned)h[1] << 16);
        pk.y = (unsigned)h[2] | ((unsigned)h[3] << 16);
        pk.z = (unsigned)h[4] | ((unsigned)h[5] << 16);
        pk.w = (unsigned)h[6] | ((unsigned)h[7] << 16);
        *(uint4*)(dstb + (size_t)sp * 128 + tl * 8) = pk;
    }
    float* ppd = pp + ((size_t)n * 16 + tb) * CV;
    for (int e = tid; e < CV; e += 256) {
        int c = e / 25, v = e - c * 25;
        float s = 0.f;
#pragma unroll
        for (int t = 0; t < 16; ++t) s += bf2f(tile[c][t * 25 + v]);
        ppd[e] = s;
    }
}

// classic pool (slow tier)
__global__ void k_pool(const float* __restrict__ x, float* __restrict__ pool) {
    int nc = blockIdx.x;
    int t  = threadIdx.x;
    const float* px = x + ((size_t)nc * T_ + t) * V_;
    float acc[V_];
#pragma unroll
    for (int v = 0; v < V_; ++v) acc[v] = px[v];
#pragma unroll
    for (int off = 32; off > 0; off >>= 1) {
#pragma unroll
        for (int v = 0; v < V_; ++v) acc[v] += __shfl_down(acc[v], off, 64);
    }
    __shared__ float sm[4][V_];
    int wave = t >> 6, lane = t & 63;
    if (lane == 0) {
#pragma unroll
        for (int v = 0; v < V_; ++v) sm[wave][v] = acc[v];
    }
    __syncthreads();
    if (t < V_) {
        float s = sm[0][t] + sm[1][t] + sm[2][t] + sm[3][t];
        pool[(size_t)nc * V_ + t] = s * (1.0f / T_);
    }
}

// ---------------------------------------------------------------------------
// k_tvals (slow tier only)
// ---------------------------------------------------------------------------
__global__ void k_tvals(const float* __restrict__ pool,
                        const float* __restrict__ W11, const float* __restrict__ b11,
                        const float* __restrict__ W12, const float* __restrict__ b12,
                        const float* __restrict__ W2,  const float* __restrict__ b2,
                        float* __restrict__ t2o, float* __restrict__ tSo) {
    int kn = blockIdx.x;
    int k = kn / N_, n = kn % N_;
    int tid = threadIdx.x;
    int r = tid >> 5, v = tid & 31;
    if (v >= V_) return;
    const float* pp = pool + (size_t)n * C_ * V_ + v;
    const float* w2 = W2 + ((size_t)k * R_ + r) * C_;
    const float* w1 = ((v < NU_) ? W11 : W12) + ((size_t)k * R_ + r) * C_;
    float a2 = b2[k * R_ + r];
    float a1 = (v < NU_) ? b11[k * R_ + r] : b12[k * R_ + r];
    for (int c = 0; c < C_; ++c) {
        float p = pp[(size_t)c * V_];
        a2 += w2[c] * p;
        a1 += w1[c] * p;
    }
    size_t idx = (((size_t)k * N_ + n) * R_ + r) * V_ + v;
    t2o[idx] = a2;
    tSo[idx] = a1;
}

// ---------------------------------------------------------------------------
// k_graphs (slow tier)
// ---------------------------------------------------------------------------
__global__ void k_graphs(const float* __restrict__ t2v, const float* __restrict__ tSv,
                         const float* __restrict__ W4, const float* __restrict__ b4,
                         float* __restrict__ graphs) {
    int kn = blockIdx.x;
    int k = kn / N_, n = kn % N_;
    int kup = (k + 1) % K_;
    __shared__ float F[R_][V_ * V_];
    __shared__ float w4s[O_][R_];
    __shared__ float b4s[O_];
    int tid = threadIdx.x;
    for (int i = tid; i < O_ * R_; i += 256) w4s[i / R_][i % R_] = W4[(size_t)k * O_ * R_ + i];
    if (tid < O_) b4s[tid] = b4[k * O_ + tid];
    for (int idx = tid; idx < R_ * V_ * V_; idx += 256) {
        int r = idx / (V_ * V_), uv = idx % (V_ * V_);
        int u = uv / V_, v = uv % V_;
        int ks = (u < NU_) ? kup : k;
        size_t base = (((size_t)ks * N_ + n) * R_ + r) * V_;
        F[r][uv] = tanhf(tSv[base + u] - t2v[base + v]);
    }
    __syncthreads();
    float* gout = graphs + ((size_t)k * N_ + n) * O_ * (V_ * V_);
    for (int idx = tid; idx < O_ * V_ * V_; idx += 256) {
        int o = idx / (V_ * V_), uv = idx % (V_ * V_);
        float a = b4s[o];
#pragma unroll
        for (int r = 0; r < R_; ++r) a += w4s[o][r] * F[r][uv];
        gout[idx] = a;
    }
}

// ---------------------------------------------------------------------------
// k_graphs2c (fast tier): pool-from-pp + tvals + F + graphs, fused; split
// over 2 o-halves for occupancy.
// ---------------------------------------------------------------------------
__global__ void k_graphs2c(const float* __restrict__ pp,
                           const float* __restrict__ W11, const float* __restrict__ b11,
                           const float* __restrict__ W12, const float* __restrict__ b12,
                           const float* __restrict__ W2,  const float* __restrict__ b2,
                           const float* __restrict__ W4,  const float* __restrict__ b4,
                           float* __restrict__ graphs) {
    int bid = blockIdx.x;
    int og = bid & 1;
    int kn = bid >> 1;
    int k = kn / N_, n = kn % N_;
    int kup = (k + 1) % K_;
    __shared__ float poolL[CV];
    __shared__ float t2s[2][R_][V_];
    __shared__ float tSs[2][R_][V_];
    __shared__ float F[R_][V_ * V_];
    __shared__ float w4s[O_][R_];
    __shared__ float b4s[O_];
    int tid = threadIdx.x;
    for (int i = tid; i < O_ * R_; i += 512) w4s[i / R_][i % R_] = W4[(size_t)k * O_ * R_ + i];
    if (tid < O_) b4s[tid] = b4[k * O_ + tid];
    const float* ppn = pp + (size_t)n * 16 * CV;
    for (int i = tid; i < CV; i += 512) {
        float s = 0.f;
#pragma unroll
        for (int tb = 0; tb < 16; ++tb) s += ppn[(size_t)tb * CV + i];
        poolL[i] = s * (1.0f / T_);
    }
    __syncthreads();
    for (int i = tid; i < 2 * R_ * V_; i += 512) {
        int ks = i / (R_ * V_);
        int rem = i - ks * (R_ * V_);
        int r = rem / V_, v = rem - r * V_;
        int kk = ks ? kup : k;
        const float* w2 = W2 + ((size_t)kk * R_ + r) * C_;
        const float* w1 = ((v < NU_) ? W11 : W12) + ((size_t)kk * R_ + r) * C_;
        float a2 = b2[kk * R_ + r];
        float a1 = (v < NU_) ? b11[kk * R_ + r] : b12[kk * R_ + r];
        for (int c = 0; c < C_; ++c) {
            float p = poolL[c * 25 + v];
            a2 += w2[c] * p;
            a1 += w1[c] * p;
        }
        t2s[ks][r][v] = a2;
        tSs[ks][r][v] = a1;
    }
    __syncthreads();
    for (int idx = tid; idx < R_ * V_ * V_; idx += 512) {
        int r = idx / (V_ * V_), uv = idx % (V_ * V_);
        int u = uv / V_, v = uv % V_;
        int ks = (u < NU_) ? 1 : 0;
        F[r][uv] = tanhf(tSs[ks][r][u] - t2s[ks][r][v]);
    }
    __syncthreads();
    float* gout = graphs + ((size_t)k * N_ + n) * O_ * (V_ * V_);
    const int half = O_ * V_ * V_ / 2;
    for (int idx = og * half + tid; idx < (og + 1) * half; idx += 512) {
        int o = idx / (V_ * V_), uv = idx % (V_ * V_);
        float a = b4s[o];
#pragma unroll
        for (int r = 0; r < R_; ++r) a += w4s[o][r] * F[r][uv];
        gout[idx] = a;
    }
}

// ---------------------------------------------------------------------------
// k_main_fast: R14 structure (256 thr, 4 blocks/CU, XCD swizzle, W3-bf16,
// pair-unrolled static addressing) + 4-SLOT Hs -> ONE barrier per pair:
//   iteration i reads slots {2i,2i+1} mod 4, writes {2i+2,2i+3} mod 4 —
//   disjoint, so the single end-of-iteration barrier both publishes the
//   writes and protects the just-read slots from next iteration's writes.
// Barriers in K-loop: 51 -> 26. G stored bf16 (uint2+ushort, proven R10)
// to keep LDS at ~30 KB -> 4 blocks/CU. WRITE_SIZE is the spill watchdog.
// ---------------------------------------------------------------------------
__global__ __launch_bounds__(256, 4) void k_main_fast(
    const unsigned short* __restrict__ xT3,  // [N][16][200][16][8] bf16 bits
    const float* __restrict__ graphs,        // [K][N][O][625]
    const float* __restrict__ Adj,           // [K][625]
    const float* __restrict__ W3,            // [K][O][C]
    const float* __restrict__ b3,            // [K][O]
    float* __restrict__ out) {

    __shared__ unsigned short Hs[4][4][NB][8];     // 16 KB, slot -> +4096 B
    __shared__ uint2 Gbf4[OG * 625];               // 10 KB (bf16 k0..3), idx o*625+v*25+u
    __shared__ unsigned short Gbf1[OG * 625];      // 2.5 KB (bf16 k4)
    __shared__ unsigned short W3kmh[K_ * OG * C_]; // 1.25 KB bf16: [k][o][c]
    __shared__ float biasS[NB];                    // 256 B

    const int tid = threadIdx.x;
    int bid = blockIdx.x;
    bid = (bid & 7) * 128 + (bid >> 3);   // XCD swizzle, bijective (1024 % 8 == 0)
    const int obase = (bid & 31) * OG;
    const int n = bid >> 5;
    const int lane = tid & 63;
    const int wv_ = tid >> 6;             // 0..3

    // ---- stage G as bf16 (graphs + Adj) ----
    const size_t kstride = (size_t)N_ * O_ * 625;
    for (int i = tid; i < OG * 625; i += 256) {
        int o = i / 625, uv = i - o * 625;
        int u = uv / 25, v = uv - u * 25;
        size_t gb = ((size_t)n * O_ + obase + o) * 625 + uv;
        float g0 = graphs[gb]               + Adj[uv];
        float g1 = graphs[gb + kstride]     + Adj[625 + uv];
        float g2 = graphs[gb + 2 * kstride] + Adj[1250 + uv];
        float g3 = graphs[gb + 3 * kstride] + Adj[1875 + uv];
        float g4 = graphs[gb + 4 * kstride] + Adj[2500 + uv];
        int idx = o * 625 + v * 25 + u;
        uint2 w; w.x = pk2(g0, g1); w.y = pk2(g2, g3);
        Gbf4[idx] = w;
        Gbf1[idx] = f2bf(g4);
    }
    // ---- stage W3 k-major, bf16 ----
    for (int i = tid; i < K_ * OG * C_; i += 256) {   // 640 scalars
        int k = i / (OG * C_);
        int rem = i - k * (OG * C_);
        int o = rem >> 6, c = rem & 63;
        W3kmh[(k * OG + o) * C_ + c] = f2bf(W3[((size_t)k * O_ + obase + o) * C_ + c]);
    }
    __syncthreads();

    // ---- in-block bias ----
    if (tid < NB) {
        int o = tid >> 5, u = tid & 31;
        float bv = 0.f;
        if (u < U_) {
            float s0 = 0.f, s1 = 0.f, s2 = 0.f, s3 = 0.f, s4 = 0.f;
            for (int v = 0; v < V_; ++v) {
                int idx = o * 625 + v * 25 + u;
                uint2 w = Gbf4[idx];
                s0 += bf_lo(w.x); s1 += bf_hi(w.x);
                s2 += bf_lo(w.y); s3 += bf_hi(w.y);
                s4 += bf2f(Gbf1[idx]);
            }
            bv = s0 * b3[0 * O_ + obase + o] + s1 * b3[1 * O_ + obase + o]
               + s2 * b3[2 * O_ + obase + o] + s3 * b3[3 * O_ + obase + o]
               + s4 * b3[4 * O_ + obase + o];
        }
        biasS[tid] = bv;
    }

    // ---- per-thread bases (h_form: wave = k-slot, lane = ncol) ----
    const int sl = wv_;                         // k-slot 0..3
    const int hncol = lane;                     // 0..63
    const int ho = hncol >> 5;
    const int hu = hncol & 31;
    const uint2* gp4 = &Gbf4[ho * 625 + hu];    // v -> +25
    const unsigned short* gp1 = &Gbf1[ho * 625 + hu];
    const unsigned short* wbh = &W3kmh[ho * C_ + sl * 8];  // k -> +OG*C_, par -> +32
    char* hwb = (char*)&Hs[0][sl][hncol][0];    // slot -> +4096 B

    auto h_form = [&](char* hwp, const int parOff /*0 or 32*/, f32x4 g, float g5) {
        float gk[5] = {g[0], g[1], g[2], g[3], g5};
        float h0 = 0.f, h1 = 0.f, h2 = 0.f, h3 = 0.f;
        float h4 = 0.f, h5 = 0.f, h6 = 0.f, h7 = 0.f;
#pragma unroll
        for (int k = 0; k < K_; ++k) {
            uint4 wk = *(const uint4*)(wbh + parOff + k * (OG * C_));
            float gv_ = gk[k];
            h0 += bf_lo(wk.x) * gv_; h1 += bf_hi(wk.x) * gv_;
            h2 += bf_lo(wk.y) * gv_; h3 += bf_hi(wk.y) * gv_;
            h4 += bf_lo(wk.z) * gv_; h5 += bf_hi(wk.z) * gv_;
            h6 += bf_lo(wk.w) * gv_; h7 += bf_hi(wk.w) * gv_;
        }
        uint4 hv;
        hv.x = cvtpk(h0, h1); hv.y = cvtpk(h2, h3);
        hv.z = cvtpk(h4, h5); hv.w = cvtpk(h6, h7);
        *(uint4*)hwp = hv;
    };
    auto ld_g = [&](int voff25, f32x4& g, float& g5) {
        if (hu < U_) {
            uint2 gw = gp4[voff25];
            g[0] = bf_lo(gw.x); g[1] = bf_hi(gw.x);
            g[2] = bf_lo(gw.y); g[3] = bf_hi(gw.y);
            g5 = bf2f(gp1[voff25]);
        } else { g = (f32x4){0.f, 0.f, 0.f, 0.f}; g5 = 0.f; }
    };

    // ---- MFMA wave grid: wm = wave (0..3, 64 t-rows each) ----
    const int wm = wv_;
    const int lr = lane & 15;
    const int eg = lane >> 4;

    f32x4 acc[4][4];
#pragma unroll
    for (int mt = 0; mt < 4; ++mt)
#pragma unroll
        for (int nt = 0; nt < 4; ++nt) acc[mt][nt] = (f32x4){0.f, 0.f, 0.f, 0.f};

    const unsigned short* An = xT3 + (size_t)n * (T_ * CV);
    const unsigned short* a0 = An + ((size_t)((wm * 4 + 0) * 200 + eg)) * 128 + lr * 8;
    const unsigned short* a1 = a0 + 200 * 128;
    const unsigned short* a2 = a0 + 400 * 128;
    const unsigned short* a3 = a0 + 600 * 128;
    const char* hrb = (const char*)&Hs[0][eg][lr][0];   // nt -> +256B, slot -> +4096B

    auto consume = [&](int sub /*elements: 0 or 512*/, int bufb /*bytes*/) {
        uint4 av0 = *(const uint4*)(a0 + sub);
        uint4 av1 = *(const uint4*)(a1 + sub);
        uint4 av2 = *(const uint4*)(a2 + sub);
        uint4 av3 = *(const uint4*)(a3 + sub);
        bf16x8 b[4];
#pragma unroll
        for (int nt = 0; nt < 4; ++nt)
            b[nt] = *(const bf16x8*)(hrb + bufb + nt * 256);
        __builtin_amdgcn_s_setprio(1);
        union { uint4 u; bf16x8 h; } c0, c1, c2, c3;
        c0.u = av0; c1.u = av1; c2.u = av2; c3.u = av3;
#pragma unroll
        for (int nt = 0; nt < 4; ++nt) acc[0][nt] = __builtin_amdgcn_mfma_f32_16x16x32_bf16(c0.h, b[nt], acc[0][nt], 0, 0, 0);
#pragma unroll
        for (int nt = 0; nt < 4; ++nt) acc[1][nt] = __builtin_amdgcn_mfma_f32_16x16x32_bf16(c1.h, b[nt], acc[1][nt], 0, 0, 0);
#pragma unroll
        for (int nt = 0; nt < 4; ++nt) acc[2][nt] = __builtin_amdgcn_mfma_f32_16x16x32_bf16(c2.h, b[nt], acc[2][nt], 0, 0, 0);
#pragma unroll
        for (int nt = 0; nt < 4; ++nt) acc[3][nt] = __builtin_amdgcn_mfma_f32_16x16x32_bf16(c3.h, b[nt], acc[3][nt], 0, 0, 0);
        __builtin_amdgcn_s_setprio(0);
    };

    // ---- prologue: form pair 0 (v=0) into slots {0,1} ----
    f32x4 gv; float gv5;
    ld_g(0, gv, gv5);
    h_form(hwb, 0, gv, gv5);            // slot 0, par0
    h_form(hwb + 4096, 32, gv, gv5);    // slot 1, par1
    __syncthreads();

    // ---- main loop: 25 pairs, ONE barrier each ----
    for (int kc2 = 0; kc2 < 25; ++kc2) {
        const int rb = (kc2 & 1) * 8192;     // read slots {0,1} or {2,3}
        const int wb = 8192 - rb;            // write slots (disjoint)
        if (kc2 + 1 < 25) ld_g((kc2 + 1) * 25, gv, gv5);   // next pair's G
        consume(0, rb);                      // chunk 2*kc2   (par0)
        consume(512, rb + 4096);             // chunk 2*kc2+1 (par1)
        if (kc2 + 1 < 25) {
            h_form(hwb + wb, 0, gv, gv5);          // next pair par0
            h_form(hwb + wb + 4096, 32, gv, gv5);  // next pair par1
        }
        __syncthreads();
        a0 += 1024; a1 += 1024; a2 += 1024; a3 += 1024;
    }

    // ---- epilogue: C/D col = lane&15 (ncol), row = eg*4 + r2 (t) ----
#pragma unroll
    for (int nt = 0; nt < 4; ++nt) {
        int ncol = nt * 16 + lr;
        int ol = ncol >> 5;
        int u  = ncol & 31;
        if (u < U_) {
            float bv = biasS[ncol];
            float* ob = out + ((size_t)n * O_ + obase + ol) * T_ * V_ + u;
#pragma unroll
            for (int mt = 0; mt < 4; ++mt) {
                int t0 = wm * 64 + mt * 16 + eg * 4;
#pragma unroll
                for (int r2 = 0; r2 < 4; ++r2)
                    ob[(size_t)(t0 + r2) * V_] = acc[mt][nt][r2] + bv;
            }
        }
    }
}

// ---------------------------------------------------------------------------
// k_main_slow (fallback, proven R2 path)
// ---------------------------------------------------------------------------
#define OB 4
#define TB 64
__global__ __launch_bounds__(256, 1) void k_main_slow(
    const float* __restrict__ x, const float* __restrict__ graphs,
    const float* __restrict__ A, const float* __restrict__ W3,
    const float* __restrict__ b3, float* __restrict__ out) {
    int bid = blockIdx.x;
    int tb = bid & 3;
    int ob = (bid >> 2) & 15;
    int n  = bid >> 6;
    int tid = threadIdx.x;
    int ol = tid >> 6;
    int tl = tid & 63;
    int t = tb * TB + tl;
    int o = ob * OB + ol;

    __shared__ float Gs[K_][OB][V_][28];
    __shared__ float W3s[K_][OB][C_];
    __shared__ float b3s[K_][OB];

    for (int i = tid; i < K_ * OB * V_ * V_; i += 256) {
        int k   = i / (OB * V_ * V_);
        int rem = i % (OB * V_ * V_);
        int oo  = rem / (V_ * V_);
        int uv  = rem % (V_ * V_);
        Gs[k][oo][uv / V_][uv % V_] =
            graphs[(((size_t)k * N_ + n) * O_ + ob * OB + oo) * (V_ * V_) + uv]
            + A[k * V_ * V_ + uv];
    }
    for (int i = tid; i < K_ * OB * C_; i += 256) {
        int k   = i / (OB * C_);
        int rem = i % (OB * C_);
        int oo  = rem / C_, c = rem % C_;
        W3s[k][oo][c] = W3[((size_t)k * O_ + ob * OB + oo) * C_ + c];
    }
    if (tid < K_ * OB) b3s[tid / OB][tid % OB] = b3[(tid / OB) * O_ + ob * OB + tid % OB];
    __syncthreads();

    float x2[K_][V_];
#pragma unroll
    for (int k = 0; k < K_; ++k)
#pragma unroll
        for (int v = 0; v < V_; ++v) x2[k][v] = b3s[k][ol];

    const float* xb = x + ((size_t)n * C_ * T_ + t) * V_;
    for (int c = 0; c < C_; ++c) {
        const float* p = xb + (size_t)c * T_ * V_;
        float xv[V_];
#pragma unroll
        for (int v = 0; v < V_; ++v) xv[v] = p[v];
#pragma unroll
        for (int k = 0; k < K_; ++k) {
            float w = W3s[k][ol][c];
#pragma unroll
            for (int v = 0; v < V_; ++v) x2[k][v] += w * xv[v];
        }
    }

    float acc[V_];
#pragma unroll
    for (int u = 0; u < V_; ++u) acc[u] = 0.0f;
#pragma unroll
    for (int k = 0; k < K_; ++k) {
#pragma unroll
        for (int u = 0; u < V_; ++u) {
            const float* gr = &Gs[k][ol][u][0];
            float s = 0.0f;
#pragma unroll
            for (int v = 0; v < V_; ++v) s += gr[v] * x2[k][v];
            acc[u] += s;
        }
    }
    float* po = out + (((size_t)n * O_ + o) * T_ + t) * V_;
#pragma unroll
    for (int u = 0; u < V_; ++u) po[u] = acc[u];
}

// ---------------------------------------------------------------------------
extern "C" void kernel_launch(void* const* d_in, const int* in_sizes, int n_in,
                              void* d_out, int out_size, void* d_ws, size_t ws_size,
                              hipStream_t stream) {
    const float* x   = (const float*)d_in[0];
    const float* A   = (const float*)d_in[1];
    const float* W11 = (const float*)d_in[2];
    const float* b11 = (const float*)d_in[3];
    const float* W12 = (const float*)d_in[4];
    const float* b12 = (const float*)d_in[5];
    const float* W2  = (const float*)d_in[6];
    const float* b2  = (const float*)d_in[7];
    const float* W3  = (const float*)d_in[8];
    const float* b3  = (const float*)d_in[9];
    const float* W4  = (const float*)d_in[10];
    const float* b4  = (const float*)d_in[11];

    float* out    = (float*)d_out;
    float* graphs = out + OUT_ELEMS;   // second tuple element

    const size_t xT_bytes = sizeof(unsigned short) * (size_t)N_ * T_ * CV;  // 26.2 MB
    const size_t pp_bytes = sizeof(float) * (size_t)N_ * 16 * CV;           //  3.3 MB
    const size_t hdr      = (size_t)(1 << 20);
    const bool fast = (ws_size >= hdr + xT_bytes + pp_bytes);

    const size_t poolElems = (size_t)N_ * C_ * V_;      // 51,200
    const size_t tElems    = (size_t)K_ * N_ * R_ * V_; // 32,000
    const size_t slowNeed  = (poolElems + 2 * tElems) * sizeof(float);

    float* scratch = (fast || ws_size >= slowNeed) ? (float*)d_ws : out;
    float* pool = scratch;
    float* t2v  = scratch + poolElems;
    float* tSv  = t2v + tElems;
    unsigned short* xT3 = (unsigned short*)((char*)d_ws + hdr);
    float* pp = (float*)((char*)d_ws + hdr + xT_bytes);

    if (fast) {
        k_xcast   <<<N_ * 16, 256, 0, stream>>>(x, xT3, pp);
        k_graphs2c<<<K_ * N_ * 2, 512, 0, stream>>>(pp, W11, b11, W12, b12, W2, b2, W4, b4, graphs);
        k_main_fast<<<N_ * 32, 256, 0, stream>>>(xT3, graphs, A, W3, b3, out);
    } else {
        k_pool  <<<N_ * C_, 256, 0, stream>>>(x, pool);
        k_tvals <<<K_ * N_, 256, 0, stream>>>(pool, W11, b11, W12, b12, W2, b2, t2v, tSv);
        k_graphs<<<K_ * N_, 256, 0, stream>>>(t2v, tSv, W4, b4, graphs);
        k_main_slow<<<N_ * (O_ / OB) * 4, 256, 0, stream>>>(x, graphs, A, W3, b3, out);
    }
}